// Round 2
// baseline (765.129 us; speedup 1.0000x reference)
//
#include <hip/hip_runtime.h>
#include <math.h>

// ---------------- problem constants (static shapes) ----------------
#define NIMG 8
#define ATOT 65472
#define NELEM (NIMG*ATOT)
#define KTOT 6960          // 2000+2000+2000+768+192
#define POST 2000
#define NMS_T 0.7f
#define TILES_PER_IMG 1668 // 528*3 + 78 + 6
#define ECAP 32768         // edges per task cap (~50x headroom over estimate)

__constant__ int c_KSEL[5]  = {2000,2000,2000,768,192};
__constant__ int c_CBASE[5] = {0,2000,4000,6000,6768};
__constant__ int c_GLVL[5]  = {32,32,32,12,3};      // ceil(k/64)
__constant__ int c_TILEPFX[6] = {0,528,1056,1584,1662,1668};

// monotone float->uint map (order-preserving for all finite floats)
__device__ __forceinline__ unsigned f2u(float f){
  unsigned b = __float_as_uint(f);
  return (b & 0x80000000u) ? ~b : (b | 0x80000000u);
}
// composite key: (value desc, global idx asc) when sorted descending
__device__ __forceinline__ unsigned long long mkkey(unsigned u, unsigned gidx){
  return ((unsigned long long)u << 32) | (unsigned long long)(0xFFFFFFFFu - gidx);
}

// in-LDS bitonic sort, descending, m = power of two (uniform per block)
__device__ void bitonic_desc(unsigned long long* sb, int m){
  int tid = threadIdx.x, nthr = blockDim.x;
  for (int size = 2; size <= m; size <<= 1){
    for (int stride = size >> 1; stride > 0; stride >>= 1){
      __syncthreads();
      for (int t = tid; t < (m >> 1); t += nthr){
        int lo = t & (stride - 1);
        int i  = ((t - lo) << 1) + lo;
        int j  = i + stride;
        bool desc = ((i & size) == 0);
        unsigned long long a = sb[i], b = sb[j];
        if (desc ? (a < b) : (a > b)) { sb[i] = b; sb[j] = a; }
      }
    }
  }
  __syncthreads();
}

// ---------------- K1a: full-GPU 12-bit histogram per (img,lvl<3) ----------------
extern "C" __global__ void __launch_bounds__(256)
k_hist(const float* __restrict__ obj, unsigned* __restrict__ hist){
  for (int e = blockIdx.x*256 + threadIdx.x; e < NELEM; e += gridDim.x*256){
    int img = e / ATOT, a = e - img*ATOT;
    int lvl;
    if (a < 49152) lvl = 0; else if (a < 61440) lvl = 1; else if (a < 64512) lvl = 2; else continue;
    unsigned u = f2u(obj[e]);
    atomicAdd(&hist[(img*5+lvl)*4096 + (u>>20)], 1u);
  }
}

// ---------------- K1b: 12-bit threshold bin per task (lvl<3) ----------------
extern "C" __global__ void __launch_bounds__(256)
k_thresh(const unsigned* __restrict__ hist, unsigned* __restrict__ T12){
  __shared__ unsigned csum[256];
  int b = blockIdx.x; int img = b/3, lvl = b%3, task = img*5+lvl;
  const unsigned* h = hist + (size_t)task*4096;
  int tid = threadIdx.x;
  unsigned s = 0;
  for (int j = 0; j < 16; ++j) s += h[tid*16 + j];
  csum[tid] = s;
  __syncthreads();
  if (tid == 0){
    unsigned k = (unsigned)c_KSEL[lvl], cum = 0, bstar = 0;
    for (int c = 255; c >= 0; --c){
      if (cum + csum[c] >= k){
        for (int j = 15; j >= 0; --j){
          cum += h[c*16 + j];
          if (cum >= k){ bstar = (unsigned)(c*16 + j); break; }
        }
        break;
      }
      cum += csum[c];
    }
    T12[task] = bstar;   // append rule: top12 >= bstar (lvl>=3 tasks stay 0 => append all)
  }
}

// ---------------- K1c: full-GPU candidate append ----------------
extern "C" __global__ void __launch_bounds__(256)
k_append(const float* __restrict__ obj, const unsigned* __restrict__ T12,
         unsigned* __restrict__ cntA, unsigned long long* __restrict__ buf){
  for (int e = blockIdx.x*256 + threadIdx.x; e < NELEM; e += gridDim.x*256){
    int img = e / ATOT, a = e - img*ATOT;
    int lvl = (a < 49152) ? 0 : (a < 61440) ? 1 : (a < 64512) ? 2 : (a < 65280) ? 3 : 4;
    int task = img*5 + lvl;
    unsigned u = f2u(obj[e]);
    if ((u >> 20) >= T12[task]){
      unsigned p = atomicAdd(&cntA[task], 1u);
      if (p < 4096u) buf[(size_t)task*4096 + p] = mkkey(u, (unsigned)a);
    }
  }
}

// ---------------- K1d: per-task sort (<=4096) + emit sorted cand + clipped boxes ----------------
extern "C" __global__ void __launch_bounds__(1024)
k_sort(const float* __restrict__ prop, const unsigned* __restrict__ cntA,
       const unsigned long long* __restrict__ buf,
       unsigned long long* __restrict__ cand, float4* __restrict__ cbox){
  __shared__ unsigned long long sb[4096];   // 32 KB
  int task = blockIdx.x, img = task/5, lvl = task%5;
  int k = c_KSEL[lvl], tid = threadIdx.x;
  int cnt = (int)min(cntA[task], 4096u);    // superset of top-k by construction
  const unsigned long long* b = buf + (size_t)task*4096;
  for (int i = tid; i < cnt; i += 1024) sb[i] = b[i];
  int m = 256; while (m < k || m < cnt) m <<= 1;
  for (int i = cnt + tid; i < m; i += 1024) sb[i] = 0ull;
  bitonic_desc(sb, m);

  const float* pr = prop + (size_t)img * ATOT * 4;
  for (int i = tid; i < k; i += 1024){
    unsigned long long key = sb[i];
    size_t slot = (size_t)img * KTOT + c_CBASE[lvl] + i;
    cand[slot] = key;
    unsigned gidx = 0xFFFFFFFFu - (unsigned)(key & 0xFFFFFFFFull);
    const float* p = pr + (size_t)gidx * 4;
    float x1 = fminf(fmaxf(p[0], 0.f), 512.f);
    float y1 = fminf(fmaxf(p[1], 0.f), 512.f);
    float x2 = fminf(fmaxf(p[2], 0.f), 512.f);
    float y2 = fminf(fmaxf(p[3], 0.f), 512.f);
    cbox[slot] = make_float4(x1, y1, x2, y2);
  }
}

// ---------------- K2a: IoU tiles -> sparse suppression edge list ----------------
extern "C" __global__ void __launch_bounds__(64)
k_mask(const float4* __restrict__ cbox, unsigned* __restrict__ ecnt,
       unsigned* __restrict__ edges){
  __shared__ float4 colb[64];
  __shared__ float  colarea[64];
  int bid = blockIdx.x;
  int img = bid / TILES_PER_IMG, r = bid % TILES_PER_IMG;
  int lvl = 0;
  while (r >= c_TILEPFX[lvl + 1]) ++lvl;
  int t = r - c_TILEPFX[lvl];
  int G = c_GLVL[lvl], k = c_KSEL[lvl];
  int gi = 0;
  while (t >= G - gi){ t -= G - gi; ++gi; }
  int gj = gi + t;
  int lane = threadIdx.x;
  const float4* cb = cbox + (size_t)img * KTOT + c_CBASE[lvl];

  int jj = gj * 64 + lane;
  float4 bb = (jj < k) ? cb[jj] : make_float4(0.f, 0.f, 0.f, 0.f);
  colb[lane] = bb;
  colarea[lane] = (bb.z - bb.x) * (bb.w - bb.y);
  __syncthreads();

  int i = gi * 64 + lane;
  if (i < k){
    float4 a = cb[i];
    float aarea = (a.z - a.x) * (a.w - a.y);
    unsigned long long word = 0ull;
    int j0 = (gi == gj) ? (lane + 1) : 0;
    int jmax = min(64, k - gj * 64);
    for (int j = j0; j < jmax; ++j){
      float4 b = colb[j];
      float ix = fminf(a.z, b.z) - fmaxf(a.x, b.x);
      if (ix > 0.f){
        float iy = fminf(a.w, b.w) - fmaxf(a.y, b.y);
        if (iy > 0.f){
          float inter = ix * iy;
          float uni = aarea + colarea[j] - inter;
          if (inter / uni > NMS_T) word |= (1ull << j);  // division to match ref rounding
        }
      }
    }
    int nb = __popcll(word);
    if (nb){
      int task = img*5 + lvl;
      unsigned base = atomicAdd(&ecnt[task], (unsigned)nb);
      unsigned* ep = edges + (size_t)task * ECAP;
      while (word){
        int j = __ffsll(word) - 1; word &= word - 1;
        if (base < ECAP) ep[base] = ((unsigned)i << 16) | (unsigned)(gj*64 + j);
        ++base;
      }
    }
  }
}

// ---------------- K2b: NMS fixpoint on edge list (exact greedy) + compaction ----------------
extern "C" __global__ void __launch_bounds__(256)
k_scan(const unsigned long long* __restrict__ cand, const unsigned* __restrict__ ecnt,
       const unsigned* __restrict__ edges, unsigned long long* __restrict__ clist,
       unsigned* __restrict__ ccnt){
  __shared__ unsigned long long keepW[32], suppW[32], initW[32];
  __shared__ unsigned wpfx[33];
  __shared__ int s_changed;
  int task = blockIdx.x, img = task/5, lvl = task%5;
  int k = c_KSEL[lvl], nW = c_GLVL[lvl], tid = threadIdx.x;

  if (tid < 32){
    unsigned long long v = 0ull;
    if (tid < nW){
      int rem = k - tid*64;
      v = (rem >= 64) ? ~0ull : ((1ull << rem) - 1ull);
    }
    initW[tid] = v; keepW[tid] = v;
  }
  __syncthreads();

  int nE = (int)min(ecnt[task], (unsigned)ECAP);
  const unsigned* E = edges + (size_t)task * ECAP;

  // greedy NMS == unique kernel of the suppression DAG; iterate to fixpoint.
  // converges in <= depth+1 iterations; deterministic (pure OR-reduction).
  for (int iter = 0; iter < 4096; ++iter){
    if (tid < 32) suppW[tid] = 0ull;
    if (tid == 0) s_changed = 0;
    __syncthreads();
    for (int e = tid; e < nE; e += 256){
      unsigned ed = E[e];
      int i = (int)(ed >> 16), j = (int)(ed & 0xFFFFu);
      if ((keepW[i >> 6] >> (i & 63)) & 1ull)
        atomicOr(&suppW[j >> 6], 1ull << (j & 63));
    }
    __syncthreads();
    if (tid < 32){
      unsigned long long nk = initW[tid] & ~suppW[tid];
      if (nk != keepW[tid]){ keepW[tid] = nk; s_changed = 1; }
    }
    __syncthreads();
    if (!s_changed) break;
  }

  // compact kept candidates (preserves sorted order within level)
  if (tid == 0){
    unsigned s = 0;
    for (int w = 0; w < nW; ++w){ wpfx[w] = s; s += (unsigned)__popcll(keepW[w]); }
    wpfx[nW] = s;
    ccnt[task] = s;
  }
  __syncthreads();
  size_t base = (size_t)img * KTOT + c_CBASE[lvl];
  for (int i = tid; i < k; i += 256){
    unsigned long long w = keepW[i >> 6];
    if ((w >> (i & 63)) & 1ull){
      unsigned long long lowmask = (i & 63) ? ((1ull << (i & 63)) - 1ull) : 0ull;
      unsigned rank = wpfx[i >> 6] + (unsigned)__popcll(w & lowmask);
      clist[base + rank] = cand[base + i];
    }
  }
}

// ---------------- K3: 5-way rank merge (no sort) + output ----------------
__device__ __forceinline__ int cntGreater(const unsigned long long* base, int len,
                                          unsigned long long x){
  int lo = 0, hi = len;          // descending array, unique keys
  while (lo < hi){
    int mid = (lo + hi) >> 1;
    if (base[mid] > x) lo = mid + 1; else hi = mid;
  }
  return lo;
}

extern "C" __global__ void __launch_bounds__(1024)
k_merge(const float* __restrict__ prop, const float* __restrict__ obj,
        const unsigned long long* __restrict__ clist, const unsigned* __restrict__ ccnt,
        float* __restrict__ out){
  __shared__ unsigned long long keys[KTOT];   // ~54.4 KB
  __shared__ int loff[6], lcnt[5];
  int img = blockIdx.x, tid = threadIdx.x;
  if (tid == 0){
    int s = 0;
    for (int l = 0; l < 5; ++l){ lcnt[l] = (int)ccnt[img*5 + l]; loff[l] = s; s += lcnt[l]; }
    loff[5] = s;
  }
  __syncthreads();
  for (int l = 0; l < 5; ++l){
    size_t gb = (size_t)img * KTOT + c_CBASE[l];
    for (int e = tid; e < lcnt[l]; e += 1024) keys[loff[l] + e] = clist[gb + e];
  }
  float* ob = out + (size_t)img * POST * 4;
  float* os = out + (size_t)NIMG * POST * 4 + (size_t)img * POST;
  for (int i = tid; i < POST*4; i += 1024) ob[i] = 0.f;
  for (int i = tid; i < POST;   i += 1024) os[i] = 0.f;
  __syncthreads();

  const float* pr = prop + (size_t)img * ATOT * 4;
  const float* o  = obj  + (size_t)img * ATOT;
  int tot = loff[5];
  for (int t = tid; t < tot; t += 1024){
    int lvl = 0;
    while (t >= loff[lvl + 1]) ++lvl;
    unsigned long long x = keys[t];
    int pos = t - loff[lvl];
    for (int l = 0; l < 5; ++l){
      if (l == lvl) continue;
      pos += cntGreater(keys + loff[l], lcnt[l], x);
    }
    if (pos < POST){
      unsigned gidx = 0xFFFFFFFFu - (unsigned)(x & 0xFFFFFFFFull);
      const float* p = pr + (size_t)gidx * 4;
      ob[pos*4 + 0] = fminf(fmaxf(p[0], 0.f), 512.f);
      ob[pos*4 + 1] = fminf(fmaxf(p[1], 0.f), 512.f);
      ob[pos*4 + 2] = fminf(fmaxf(p[2], 0.f), 512.f);
      ob[pos*4 + 3] = fminf(fmaxf(p[3], 0.f), 512.f);
      double s = 1.0 / (1.0 + exp(-(double)o[gidx]));  // correctly-rounded f32 sigmoid
      os[pos] = (float)s;
    }
  }
}

// ---------------- launch ----------------
extern "C" void kernel_launch(void* const* d_in, const int* in_sizes, int n_in,
                              void* d_out, int out_size, void* d_ws, size_t ws_size,
                              hipStream_t stream){
  const float* prop = (const float*)d_in[0];
  const float* obj  = (const float*)d_in[1];
  char* ws = (char*)d_ws;
  // ws layout (bytes):
  unsigned*           hist = (unsigned*)(ws);                        // 40*4096*4 = 655360
  unsigned*           cntA = (unsigned*)(ws + 655360);               // 160 -> 655520
  unsigned*           ecnt = (unsigned*)(ws + 655520);               // 160 -> 655680
  unsigned*           T12  = (unsigned*)(ws + 655680);               // 160 -> 655840
  unsigned*           ccnt = (unsigned*)(ws + 655840);               // 160 -> 656000
  unsigned long long* buf  = (unsigned long long*)(ws + 656000);     // 40*4096*8 = 1310720 -> 1966720
  unsigned long long* cand = (unsigned long long*)(ws + 1966720);    // 8*6960*8 = 445440 -> 2412160
  unsigned long long* clist= (unsigned long long*)(ws + 2412160);    // 445440 -> 2857600
  float4*             cbox = (float4*)(ws + 2857600);                // 8*6960*16 = 890880 -> 3748480
  unsigned*           edges= (unsigned*)(ws + 3748480);              // 40*32768*4 = 5242880 -> 8991360

  hipMemsetAsync(ws, 0, 656000, stream);  // hist + cntA + ecnt + T12 + ccnt in one shot
  hipLaunchKernelGGL(k_hist,   dim3(512), dim3(256), 0, stream, obj, hist);
  hipLaunchKernelGGL(k_thresh, dim3(24),  dim3(256), 0, stream, hist, T12);
  hipLaunchKernelGGL(k_append, dim3(512), dim3(256), 0, stream, obj, T12, cntA, buf);
  hipLaunchKernelGGL(k_sort,   dim3(40),  dim3(1024), 0, stream, prop, cntA, buf, cand, cbox);
  hipLaunchKernelGGL(k_mask,   dim3(NIMG * TILES_PER_IMG), dim3(64), 0, stream, cbox, ecnt, edges);
  hipLaunchKernelGGL(k_scan,   dim3(40),  dim3(256), 0, stream, cand, ecnt, edges, clist, ccnt);
  hipLaunchKernelGGL(k_merge,  dim3(NIMG), dim3(1024), 0, stream, prop, obj, clist, ccnt, (float*)d_out);
}

// Round 3
// 252.050 us; speedup vs baseline: 3.0356x; 3.0356x over previous
//
#include <hip/hip_runtime.h>
#include <math.h>

// ---------------- problem constants (static shapes) ----------------
#define NIMG 8
#define ATOT 65472
#define KTOT 6960          // 2000+2000+2000+768+192
#define POST 2000
#define NMS_T 0.7f
#define TILES_PER_IMG 1668 // 528*3 + 78 + 6
#define ESEG 1024          // edges per (task,gi) segment cap

__constant__ int c_LOFF[5]  = {0,49152,61440,64512,65280};
__constant__ int c_KSEL[5]  = {2000,2000,2000,768,192};
__constant__ int c_CBASE[5] = {0,2000,4000,6000,6768};
__constant__ int c_GLVL[5]  = {32,32,32,12,3};      // ceil(k/64)
__constant__ int c_TILEPFX[6] = {0,528,1056,1584,1662,1668};
// slice tables: 13 append-slots per image (first 11 are also hist-slots, lvl<3)
__constant__ int c_SLVL[13]  = {0,0,0,0,0,0,0,0,1,1,2,3,4};
__constant__ int c_SOFF13[13]= {0,6144,12288,18432,24576,30720,36864,43008, 0,6144, 0,0,0};
__constant__ int c_SLEN[13]  = {6144,6144,6144,6144,6144,6144,6144,6144, 6144,6144, 3072,768,192};
__constant__ int c_HS0[3] = {0,8,10};   // first hist-slot per lvl
__constant__ int c_HSN[3] = {8,2,1};    // hist-slots per lvl

// monotone float->uint map (order-preserving for all finite floats)
__device__ __forceinline__ unsigned f2u(float f){
  unsigned b = __float_as_uint(f);
  return (b & 0x80000000u) ? ~b : (b | 0x80000000u);
}
// composite key: (value desc, global idx asc) when sorted descending
__device__ __forceinline__ unsigned long long mkkey(unsigned u, unsigned gidx){
  return ((unsigned long long)u << 32) | (unsigned long long)(0xFFFFFFFFu - gidx);
}

// in-LDS bitonic sort, descending, m = power of two (uniform per block)
__device__ void bitonic_desc(unsigned long long* sb, int m){
  int tid = threadIdx.x, nthr = blockDim.x;
  for (int size = 2; size <= m; size <<= 1){
    for (int stride = size >> 1; stride > 0; stride >>= 1){
      __syncthreads();
      for (int t = tid; t < (m >> 1); t += nthr){
        int lo = t & (stride - 1);
        int i  = ((t - lo) << 1) + lo;
        int j  = i + stride;
        bool desc = ((i & size) == 0);
        unsigned long long a = sb[i], b = sb[j];
        if (desc ? (a < b) : (a > b)) { sb[i] = b; sb[j] = a; }
      }
    }
  }
  __syncthreads();
}

// ---------------- K1a: per-block LDS 12-bit histogram (lvl<3), private output ----------------
extern "C" __global__ void __launch_bounds__(256)
k_hist(const float* __restrict__ obj, unsigned* __restrict__ hist){
  __shared__ unsigned h[4096];
  int bid = blockIdx.x, img = bid / 11, slot = bid % 11;
  int lvl = c_SLVL[slot], len = c_SLEN[slot], tid = threadIdx.x;
  for (int i = tid; i < 4096; i += 256) h[i] = 0u;
  __syncthreads();
  const float* o = obj + (size_t)img * ATOT + c_LOFF[lvl] + c_SOFF13[slot];
  for (int i = tid; i < len; i += 256)
    atomicAdd(&h[f2u(o[i]) >> 20], 1u);
  __syncthreads();
  unsigned* out = hist + (size_t)bid * 4096;
  for (int i = tid; i < 4096; i += 256) out[i] = h[i];
}

// ---------------- K1b: 12-bit threshold bin per (img,lvl<3) ----------------
extern "C" __global__ void __launch_bounds__(256)
k_thresh(const unsigned* __restrict__ hist, unsigned* __restrict__ T12){
  __shared__ unsigned csum[256];
  int b = blockIdx.x, img = b / 3, lvl = b % 3, tid = threadIdx.x;
  int hs0 = c_HS0[lvl], hsn = c_HSN[lvl];
  unsigned s = 0;
  for (int hs = 0; hs < hsn; ++hs){
    const unsigned* h = hist + (size_t)(img * 11 + hs0 + hs) * 4096;
    for (int j = 0; j < 16; ++j) s += h[tid * 16 + j];
  }
  csum[tid] = s;
  __syncthreads();
  if (tid == 0){
    unsigned k = (unsigned)c_KSEL[lvl], cum = 0, bstar = 0;
    for (int c = 255; c >= 0; --c){
      if (cum + csum[c] >= k){
        for (int j = 15; j >= 0; --j){
          unsigned bv = 0;
          for (int hs = 0; hs < hsn; ++hs)
            bv += hist[(size_t)(img * 11 + hs0 + hs) * 4096 + c * 16 + j];
          cum += bv;
          if (cum >= k){ bstar = (unsigned)(c * 16 + j); break; }
        }
        break;
      }
      cum += csum[c];
    }
    T12[img * 5 + lvl] = bstar;
  }
}

// ---------------- K1c: slice append via LDS buffer, ONE global atomic per block ----------------
extern "C" __global__ void __launch_bounds__(256)
k_append(const float* __restrict__ obj, const unsigned* __restrict__ T12,
         unsigned* __restrict__ cntA, unsigned long long* __restrict__ buf){
  __shared__ unsigned long long lbuf[2048];
  __shared__ unsigned lcnt, gbase;
  int bid = blockIdx.x, img = bid / 13, slot = bid % 13;
  int lvl = c_SLVL[slot], len = c_SLEN[slot], task = img * 5 + lvl, tid = threadIdx.x;
  unsigned T = (lvl < 3) ? T12[task] : 0u;
  if (tid == 0) lcnt = 0u;
  __syncthreads();
  int abase = c_LOFF[lvl] + c_SOFF13[slot];
  const float* o = obj + (size_t)img * ATOT;
  for (int i = tid; i < len; i += 256){
    int a = abase + i;
    unsigned u = f2u(o[a]);
    if ((u >> 20) >= T){
      unsigned p = atomicAdd(&lcnt, 1u);     // LDS atomic: cheap
      if (p < 2048u) lbuf[p] = mkkey(u, (unsigned)a);
    }
  }
  __syncthreads();
  unsigned c = min(lcnt, 2048u);
  if (tid == 0) gbase = atomicAdd(&cntA[task], c);   // one global atomic per block
  __syncthreads();
  unsigned long long* bp = buf + (size_t)task * 4096;
  for (unsigned i = tid; i < c; i += 256){
    unsigned p = gbase + i;
    if (p < 4096u) bp[p] = lbuf[i];
  }
}

// ---------------- K1d: per-task sort (<=4096) + emit sorted cand + clipped boxes ----------------
extern "C" __global__ void __launch_bounds__(1024)
k_sort(const float* __restrict__ prop, const unsigned* __restrict__ cntA,
       const unsigned long long* __restrict__ buf,
       unsigned long long* __restrict__ cand, float4* __restrict__ cbox){
  __shared__ unsigned long long sb[4096];   // 32 KB
  int task = blockIdx.x, img = task / 5, lvl = task % 5;
  int k = c_KSEL[lvl], tid = threadIdx.x;
  int cnt = (int)min(cntA[task], 4096u);    // superset of top-k by construction
  const unsigned long long* b = buf + (size_t)task * 4096;
  for (int i = tid; i < cnt; i += 1024) sb[i] = b[i];
  int m = 256; while (m < k || m < cnt) m <<= 1;
  for (int i = cnt + tid; i < m; i += 1024) sb[i] = 0ull;
  bitonic_desc(sb, m);

  const float4* pr = (const float4*)(prop + (size_t)img * ATOT * 4);
  for (int i = tid; i < k; i += 1024){
    unsigned long long key = sb[i];
    size_t slot = (size_t)img * KTOT + c_CBASE[lvl] + i;
    cand[slot] = key;
    unsigned gidx = 0xFFFFFFFFu - (unsigned)(key & 0xFFFFFFFFull);
    float4 p = pr[gidx];
    float x1 = fminf(fmaxf(p.x, 0.f), 512.f);
    float y1 = fminf(fmaxf(p.y, 0.f), 512.f);
    float x2 = fminf(fmaxf(p.z, 0.f), 512.f);
    float y2 = fminf(fmaxf(p.w, 0.f), 512.f);
    cbox[slot] = make_float4(x1, y1, x2, y2);
  }
}

// ---------------- K2a: IoU tiles -> segmented edge lists (1 atomic/wave) ----------------
extern "C" __global__ void __launch_bounds__(64)
k_mask(const float4* __restrict__ cbox, unsigned* __restrict__ ecnt,
       unsigned* __restrict__ eseg){
  __shared__ float4 colb[64];
  __shared__ float  colarea[64];
  int bid = blockIdx.x;
  int img = bid / TILES_PER_IMG, r = bid % TILES_PER_IMG;
  int lvl = 0;
  while (r >= c_TILEPFX[lvl + 1]) ++lvl;
  int t = r - c_TILEPFX[lvl];
  int G = c_GLVL[lvl], k = c_KSEL[lvl];
  int gi = 0;
  while (t >= G - gi){ t -= G - gi; ++gi; }
  int gj = gi + t;
  int lane = threadIdx.x;
  const float4* cb = cbox + (size_t)img * KTOT + c_CBASE[lvl];

  int jj = gj * 64 + lane;
  float4 bb = (jj < k) ? cb[jj] : make_float4(0.f, 0.f, 0.f, 0.f);
  colb[lane] = bb;
  colarea[lane] = (bb.z - bb.x) * (bb.w - bb.y);
  __syncthreads();

  int i = gi * 64 + lane;
  unsigned long long word = 0ull;
  if (i < k){
    float4 a = cb[i];
    float aarea = (a.z - a.x) * (a.w - a.y);
    int j0 = (gi == gj) ? (lane + 1) : 0;
    int jmax = min(64, k - gj * 64);
    for (int j = j0; j < jmax; ++j){
      float4 b = colb[j];
      float ix = fminf(a.z, b.z) - fmaxf(a.x, b.x);
      if (ix > 0.f){
        float iy = fminf(a.w, b.w) - fmaxf(a.y, b.y);
        if (iy > 0.f){
          float inter = ix * iy;
          float uni = aarea + colarea[j] - inter;
          if (inter / uni > NMS_T) word |= (1ull << j);  // division to match ref rounding
        }
      }
    }
  }
  // wave-aggregated emission: prefix-scan edge counts, ONE atomic per wave
  int nb = __popcll(word);
  int pfx = nb;
  for (int d = 1; d < 64; d <<= 1){
    int v = __shfl_up(pfx, d);
    if (lane >= d) pfx += v;
  }
  int total = __shfl(pfx, 63);
  if (total > 0){
    int task = img * 5 + lvl;
    unsigned basev = 0;
    if (lane == 0) basev = atomicAdd(&ecnt[task * 32 + gi], (unsigned)total);
    basev = __shfl(basev, 0);
    unsigned idx = basev + (unsigned)(pfx - nb);
    unsigned* ep = eseg + (size_t)(task * 32 + gi) * ESEG;
    while (word){
      int j = __ffsll(word) - 1; word &= word - 1;
      if (idx < ESEG) ep[idx] = ((unsigned)i << 16) | (unsigned)(gj * 64 + j);
      ++idx;
    }
  }
}

// ---------------- K2b: NMS fixpoint on LDS edge list (exact greedy) + compaction ----------------
extern "C" __global__ void __launch_bounds__(256)
k_scan(const unsigned long long* __restrict__ cand, const unsigned* __restrict__ ecnt,
       const unsigned* __restrict__ eseg, unsigned long long* __restrict__ clist,
       unsigned* __restrict__ ccnt){
  __shared__ unsigned long long keepW[32], suppW[32], initW[32];
  __shared__ unsigned soff[33];
  __shared__ unsigned ledge[6144];   // 24 KB edge cache
  __shared__ unsigned wpfx[33];
  __shared__ int s_changed;
  int task = blockIdx.x, img = task / 5, lvl = task % 5;
  int k = c_KSEL[lvl], nW = c_GLVL[lvl], tid = threadIdx.x;

  if (tid == 0){
    unsigned s = 0;
    for (int w = 0; w < nW; ++w){ soff[w] = s; s += min(ecnt[task * 32 + w], (unsigned)ESEG); }
    soff[nW] = s;
  }
  if (tid < 32){
    unsigned long long v = 0ull;
    if (tid < nW){
      int rem = k - tid * 64;
      v = (rem >= 64) ? ~0ull : ((1ull << rem) - 1ull);
    }
    initW[tid] = v; keepW[tid] = v;
  }
  __syncthreads();
  // stage edges into LDS (global fallback for overflow beyond 6144)
  for (int w = 0; w < nW; ++w){
    unsigned c = soff[w + 1] - soff[w];
    const unsigned* ep = eseg + (size_t)(task * 32 + w) * ESEG;
    for (unsigned e = tid; e < c; e += 256){
      unsigned p = soff[w] + e;
      if (p < 6144u) ledge[p] = ep[e];
    }
  }
  __syncthreads();

  // greedy NMS == unique kernel of the suppression DAG (edges i<j only);
  // Jacobi iteration converges in <= depth+1 rounds, deterministic.
  for (int iter = 0; iter < 4096; ++iter){
    if (tid < 32) suppW[tid] = 0ull;
    if (tid == 0) s_changed = 0;
    __syncthreads();
    for (int w = 0; w < nW; ++w){
      unsigned c = soff[w + 1] - soff[w];
      const unsigned* ep = eseg + (size_t)(task * 32 + w) * ESEG;
      for (unsigned e = tid; e < c; e += 256){
        unsigned p = soff[w] + e;
        unsigned ed = (p < 6144u) ? ledge[p] : ep[e];
        int i = (int)(ed >> 16), j = (int)(ed & 0xFFFFu);
        if ((keepW[i >> 6] >> (i & 63)) & 1ull)
          atomicOr(&suppW[j >> 6], 1ull << (j & 63));
      }
    }
    __syncthreads();
    if (tid < 32){
      unsigned long long nk = initW[tid] & ~suppW[tid];
      if (nk != keepW[tid]){ keepW[tid] = nk; s_changed = 1; }
    }
    __syncthreads();
    if (!s_changed) break;
  }

  // compact kept candidates (preserves sorted order within level)
  if (tid == 0){
    unsigned s = 0;
    for (int w = 0; w < nW; ++w){ wpfx[w] = s; s += (unsigned)__popcll(keepW[w]); }
    wpfx[nW] = s;
    ccnt[task] = s;
  }
  __syncthreads();
  size_t base = (size_t)img * KTOT + c_CBASE[lvl];
  for (int i = tid; i < k; i += 256){
    unsigned long long w = keepW[i >> 6];
    if ((w >> (i & 63)) & 1ull){
      unsigned long long lowmask = (i & 63) ? ((1ull << (i & 63)) - 1ull) : 0ull;
      unsigned rank = wpfx[i >> 6] + (unsigned)__popcll(w & lowmask);
      clist[base + rank] = cand[base + i];
    }
  }
}

// ---------------- K3: 5-way rank merge (no sort), 2 blocks/image ----------------
__device__ __forceinline__ int cntGreater(const unsigned long long* base, int len,
                                          unsigned long long x){
  int lo = 0, hi = len;          // descending array, unique keys
  while (lo < hi){
    int mid = (lo + hi) >> 1;
    if (base[mid] > x) lo = mid + 1; else hi = mid;
  }
  return lo;
}

extern "C" __global__ void __launch_bounds__(1024)
k_merge(const float* __restrict__ prop, const float* __restrict__ obj,
        const unsigned long long* __restrict__ clist, const unsigned* __restrict__ ccnt,
        float* __restrict__ out){
  __shared__ unsigned long long keys[KTOT];   // ~54.4 KB
  __shared__ int loff[6], lcnt[5];
  int img = blockIdx.x >> 1, half = blockIdx.x & 1, tid = threadIdx.x;
  if (tid == 0){
    int s = 0;
    for (int l = 0; l < 5; ++l){ lcnt[l] = (int)ccnt[img * 5 + l]; loff[l] = s; s += lcnt[l]; }
    loff[5] = s;
  }
  __syncthreads();
  for (int l = 0; l < 5; ++l){
    size_t gb = (size_t)img * KTOT + c_CBASE[l];
    for (int e = tid; e < lcnt[l]; e += 1024) keys[loff[l] + e] = clist[gb + e];
  }
  __syncthreads();

  const float4* pr = (const float4*)(prop + (size_t)img * ATOT * 4);
  const float*  o  = obj  + (size_t)img * ATOT;
  float* ob = out + (size_t)img * POST * 4;
  float* os = out + (size_t)NIMG * POST * 4 + (size_t)img * POST;
  int tot = loff[5];
  for (int tt = tid; ; tt += 1024){               // this block handles keys t = 2*tt+half
    int t = 2 * tt + half;
    if (t >= tot) break;
    int lvl = 0;
    while (t >= loff[lvl + 1]) ++lvl;
    unsigned long long x = keys[t];
    int pos = t - loff[lvl];
    for (int l = 0; l < 5; ++l){
      if (l == lvl) continue;
      pos += cntGreater(keys + loff[l], lcnt[l], x);
    }
    if (pos < POST){
      unsigned gidx = 0xFFFFFFFFu - (unsigned)(x & 0xFFFFFFFFull);
      float4 p = pr[gidx];
      ob[pos * 4 + 0] = fminf(fmaxf(p.x, 0.f), 512.f);
      ob[pos * 4 + 1] = fminf(fmaxf(p.y, 0.f), 512.f);
      ob[pos * 4 + 2] = fminf(fmaxf(p.z, 0.f), 512.f);
      ob[pos * 4 + 3] = fminf(fmaxf(p.w, 0.f), 512.f);
      double s = 1.0 / (1.0 + exp(-(double)o[gidx]));  // correctly-rounded f32 sigmoid
      os[pos] = (float)s;
    }
  }
}

// ---------------- launch ----------------
extern "C" void kernel_launch(void* const* d_in, const int* in_sizes, int n_in,
                              void* d_out, int out_size, void* d_ws, size_t ws_size,
                              hipStream_t stream){
  const float* prop = (const float*)d_in[0];
  const float* obj  = (const float*)d_in[1];
  char* ws = (char*)d_ws;
  // ws layout (bytes):
  unsigned*           cntA = (unsigned*)(ws);                        // 160        -> 160
  unsigned*           ecnt = (unsigned*)(ws + 160);                  // 40*32*4    -> 5280
  unsigned*           T12  = (unsigned*)(ws + 5280);                 // 160        -> 5440
  unsigned*           ccnt = (unsigned*)(ws + 5440);                 // 160        -> 5600 (pad->5632)
  unsigned long long* buf  = (unsigned long long*)(ws + 5632);       // 40*4096*8  -> 1316352
  unsigned long long* cand = (unsigned long long*)(ws + 1316352);    // 8*6960*8   -> 1761792
  unsigned long long* clist= (unsigned long long*)(ws + 1761792);    // 445440     -> 2207232
  float4*             cbox = (float4*)(ws + 2207232);                // 8*6960*16  -> 3098112
  unsigned*           hist = (unsigned*)(ws + 3098112);              // 88*4096*4  -> 4539904
  unsigned*           eseg = (unsigned*)(ws + 4539904);              // 40*32*1024*4 -> 9782784

  hipMemsetAsync(ws, 0, 5280, stream);                          // cntA + ecnt
  hipMemsetAsync(d_out, 0, (size_t)out_size * sizeof(float), stream);
  hipLaunchKernelGGL(k_hist,   dim3(88),  dim3(256),  0, stream, obj, hist);
  hipLaunchKernelGGL(k_thresh, dim3(24),  dim3(256),  0, stream, hist, T12);
  hipLaunchKernelGGL(k_append, dim3(104), dim3(256),  0, stream, obj, T12, cntA, buf);
  hipLaunchKernelGGL(k_sort,   dim3(40),  dim3(1024), 0, stream, prop, cntA, buf, cand, cbox);
  hipLaunchKernelGGL(k_mask,   dim3(NIMG * TILES_PER_IMG), dim3(64), 0, stream, cbox, ecnt, eseg);
  hipLaunchKernelGGL(k_scan,   dim3(40),  dim3(256),  0, stream, cand, ecnt, eseg, clist, ccnt);
  hipLaunchKernelGGL(k_merge,  dim3(16),  dim3(1024), 0, stream, prop, obj, clist, ccnt, (float*)d_out);
}